// Round 8
// baseline (305.050 us; speedup 1.0000x reference)
//
#include <hip/hip_runtime.h>
#include <hip/hip_bf16.h>
#include <cstdint>
#include <cstddef>

// K(x,y) = exp(-0.5*||x-y||^2) + 0.1*(x.y^T + 1)^3
// x,y: (8192, 256) fp32. out: (8192, 8192) fp32.
//
// R8 = R1's frame (best: 290us; BK=64 single-buffered lockstep, both-sides
// row&7 XOR swizzle, plain stores, 2D grid, 16x16x32 MFMA) with ONE change:
// TRANSPOSED EPILOGUE. The MFMA C/D layout forces scalar stores (a thread's
// 4 acc regs are 4 consecutive ROWS, same column) -> 64 global_store_dword
// per thread in 64-B half-line segments, in every variant R0-R7. Here each
// wave reuses its 8 KB quarter of the dead As/Bs LDS to transpose its 64x64
// sub-tile: scatter epilogue values to LDS, read back as float4, store
// dwordx4 -> 16 store instrs/thread, full 128-B line segments.
// LDS transpose layout (per wave, 64 rows x 8 granules of 16 B, stride 32
// words): granule g of row r lives at g^(r&7). Write: 2 lanes/bank = free;
// read: uniform 8 lanes/granule-group = b128 optimal. Wave-internal only
// (no barriers; compiler inserts lgkmcnt).

#define NROWS 8192
#define DK    256
#define BM    128
#define BN    128
#define BK    64

typedef __bf16 bf16_8 __attribute__((ext_vector_type(8)));
typedef float  f32x4  __attribute__((ext_vector_type(4)));

__device__ __forceinline__ unsigned short f2bf(float f) {
    unsigned int u = __builtin_bit_cast(unsigned int, f);
    u = (u + 0x7FFFu + ((u >> 16) & 1u)) >> 16;  // round-to-nearest-even
    return (unsigned short)u;
}

// ---------------------------------------------------------------------------
// Prep: fp32 -> bf16 conversion + row squared-norms.
// ---------------------------------------------------------------------------
__global__ __launch_bounds__(64) void prep_kernel(
    const float* __restrict__ x, const float* __restrict__ y,
    unsigned short* __restrict__ xb, unsigned short* __restrict__ yb,
    float* __restrict__ x2, float* __restrict__ y2)
{
    const int row  = blockIdx.x;
    const int lane = threadIdx.x;          // 0..63, 4 floats each = 256
    const size_t base = (size_t)row * DK + lane * 4;

    const float4 vx = *(const float4*)(x + base);
    const float4 vy = *(const float4*)(y + base);

    ushort4 hx = make_ushort4(f2bf(vx.x), f2bf(vx.y), f2bf(vx.z), f2bf(vx.w));
    ushort4 hy = make_ushort4(f2bf(vy.x), f2bf(vy.y), f2bf(vy.z), f2bf(vy.w));
    *(ushort4*)(xb + base) = hx;
    *(ushort4*)(yb + base) = hy;

    float sx = vx.x * vx.x + vx.y * vx.y + vx.z * vx.z + vx.w * vx.w;
    float sy = vy.x * vy.x + vy.y * vy.y + vy.z * vy.z + vy.w * vy.w;
    #pragma unroll
    for (int off = 32; off > 0; off >>= 1) {
        sx += __shfl_down(sx, off);
        sy += __shfl_down(sy, off);
    }
    if (lane == 0) {
        x2[row] = sx;
        y2[row] = sy;
    }
}

// ---------------------------------------------------------------------------
// GEMM + fused epilogue. C = x_bf @ y_bf^T with 16x16x32 bf16 MFMA.
// Block = 256 threads = 4 waves in 2x2, each wave owns a 64x64 sub-tile.
// K-loop identical to R1. Epilogue transposes through LDS (see header).
// ---------------------------------------------------------------------------
__global__ __launch_bounds__(256) void gemm_ep_kernel(
    const unsigned short* __restrict__ xb, const unsigned short* __restrict__ yb,
    const float* __restrict__ x2, const float* __restrict__ y2,
    float* __restrict__ out)
{
    // 32 KB: As (16 KB) + Bs (16 KB) during K-loop; reused as 4 x 8 KB
    // per-wave fp32 transpose buffers in the epilogue.
    __shared__ __align__(16) unsigned char smem[2 * BM * BK + 2 * BN * BK];
    unsigned short* As = (unsigned short*)smem;
    unsigned short* Bs = As + BM * BK;

    const int tid  = threadIdx.x;
    const int wave = tid >> 6;
    const int lane = tid & 63;
    const int bm   = blockIdx.x;
    const int bn   = blockIdx.y;

    const int wm = (wave & 1) * 64;   // wave's row offset in 128-tile
    const int wn = (wave >> 1) * 64;  // wave's col offset in 128-tile

    // --- staging: tile is 128 rows x 64 cols bf16 = 16 KB = 16 chunks of
    // 1 KiB. Wave w stages chunks 4w..4w+3 of A and B (8 global_load_lds).
    const int subrow = lane >> 3;                 // 0..7 row within chunk
    const int sslot  = (lane & 7) ^ subrow;       // pre-swizzled global slot
    const size_t laneoff = (size_t)subrow * DK + sslot * 8;

    const unsigned short* gA[4];
    const unsigned short* gB[4];
    unsigned short* lA[4];
    unsigned short* lB[4];
    #pragma unroll
    for (int m = 0; m < 4; ++m) {
        const int c = wave * 4 + m;               // chunk id, rows c*8..c*8+7
        gA[m] = xb + (size_t)(bm * BM + c * 8) * DK + laneoff;
        gB[m] = yb + (size_t)(bn * BN + c * 8) * DK + laneoff;
        lA[m] = &As[c * 512];                     // 512 ushort = 1 KiB
        lB[m] = &Bs[c * 512];
    }

    f32x4 acc[4][4];
    #pragma unroll
    for (int i = 0; i < 4; ++i)
        #pragma unroll
        for (int j = 0; j < 4; ++j)
            acc[i][j] = (f32x4){0.f, 0.f, 0.f, 0.f};

    const int quad = lane >> 4;   // 0..3
    const int l15  = lane & 15;
    const int l7   = l15 & 7;     // == row&7 for every fragment row we read

    const int rbaseA = (wm + l15) * BK;   // ushort index of row start
    const int rbaseB = (wn + l15) * BK;

    #pragma unroll
    for (int kt = 0; kt < DK; kt += BK) {
        #pragma unroll
        for (int m = 0; m < 4; ++m) {
            __builtin_amdgcn_global_load_lds(
                (const __attribute__((address_space(1))) void*)(gA[m] + kt),
                (__attribute__((address_space(3))) void*)lA[m], 16, 0, 0);
            __builtin_amdgcn_global_load_lds(
                (const __attribute__((address_space(1))) void*)(gB[m] + kt),
                (__attribute__((address_space(3))) void*)lB[m], 16, 0, 0);
        }
        __syncthreads();

        // Two K-steps of 32 from this 64-wide tile.
        #pragma unroll
        for (int kk = 0; kk < 2; ++kk) {
            const int slot = ((kk << 2) | quad) ^ l7;   // swizzled 16-B slot
            bf16_8 afr[4], bfr[4];
            #pragma unroll
            for (int i = 0; i < 4; ++i)
                afr[i] = *(const bf16_8*)&As[rbaseA + i * 16 * BK + slot * 8];
            #pragma unroll
            for (int j = 0; j < 4; ++j)
                bfr[j] = *(const bf16_8*)&Bs[rbaseB + j * 16 * BK + slot * 8];

            #pragma unroll
            for (int i = 0; i < 4; ++i)
                #pragma unroll
                for (int j = 0; j < 4; ++j)
                    acc[i][j] = __builtin_amdgcn_mfma_f32_16x16x32_bf16(
                        afr[i], bfr[j], acc[i][j], 0, 0, 0);
        }
        __syncthreads();   // last iter: all waves done with As/Bs -> reusable
    }

    // --- transposed epilogue -----------------------------------------------
    // C/D layout (m89/m91): wave-local row = i*16 + quad*4 + r,
    //                       wave-local col = l15 + j*16.
    float* Ep = (float*)smem + wave * 2048;   // this wave's 8 KB

    const int mT = bm * BM + wm;
    const int nT = bn * BN + wn;

    float y2v[4];
    #pragma unroll
    for (int j = 0; j < 4; ++j) y2v[j] = y2[nT + l15 + j * 16];

    #pragma unroll
    for (int h = 0; h < 2; ++h) {             // half = 32 cols
        // scatter epilogue values into LDS (transpose staging)
        #pragma unroll
        for (int i = 0; i < 4; ++i) {
            #pragma unroll
            for (int r = 0; r < 4; ++r) {
                const int row = i * 16 + quad * 4 + r;
                const float xv = x2[mT + row];
                #pragma unroll
                for (int jh = 0; jh < 2; ++jh) {
                    const int j    = h * 2 + jh;
                    const int lcol = l15 + jh * 16;          // 0..31
                    const float xy = acc[i][j][r];
                    float s = xv + y2v[j] - 2.0f * xy;
                    s = fmaxf(s, 0.0f);
                    const float e  = __expf(-0.5f * s);
                    const float pq = xy + 1.0f;
                    const float v  = fmaf(0.1f, pq * pq * pq, e);
                    // granule (lcol>>2) of row lives at granule ^(row&7)
                    Ep[row * 32 + (((lcol >> 2) ^ (row & 7)) << 2) + (lcol & 3)] = v;
                }
            }
        }
        // read back transposed, store as float4 (wave-internal; lgkmcnt only)
        #pragma unroll
        for (int p = 0; p < 8; ++p) {
            const int row = p * 8 + (lane >> 3);
            const int g   = lane & 7;                         // global granule
            const int gs  = g ^ (lane >> 3);                  // swizzled (row&7 == lane>>3)
            const f32x4 v4 = *(const f32x4*)&Ep[row * 32 + gs * 4];
            *(f32x4*)&out[(size_t)(mT + row) * NROWS + nT + h * 32 + g * 4] = v4;
        }
    }
}

// ---------------------------------------------------------------------------
extern "C" void kernel_launch(void* const* d_in, const int* in_sizes, int n_in,
                              void* d_out, int out_size, void* d_ws, size_t ws_size,
                              hipStream_t stream) {
    const float* x = (const float*)d_in[0];
    const float* y = (const float*)d_in[1];
    float* out = (float*)d_out;

    char* ws = (char*)d_ws;
    unsigned short* xb = (unsigned short*)ws;                                  // 4 MB
    unsigned short* yb = (unsigned short*)(ws + (size_t)NROWS * DK * 2);       // 4 MB
    float* x2 = (float*)(ws + (size_t)2 * NROWS * DK * 2);                     // 32 KB
    float* y2 = x2 + NROWS;                                                    // 32 KB

    prep_kernel<<<NROWS, 64, 0, stream>>>(x, y, xb, yb, x2, y2);

    dim3 grid(NROWS / BM, NROWS / BN);
    gemm_ep_kernel<<<grid, 256, 0, stream>>>(xb, yb, x2, y2, out);
}

// Round 9
// 301.305 us; speedup vs baseline: 1.0124x; 1.0124x over previous
//
#include <hip/hip_runtime.h>
#include <hip/hip_bf16.h>
#include <cstdint>
#include <cstddef>

// K(x,y) = exp(-0.5*||x-y||^2) + 0.1*(x.y^T + 1)^3
// x,y: (8192, 256) fp32. out: (8192, 8192) fp32.
//
// R9 = R1's K-loop (best: 290us) + m-split transposed epilogue producing
// 256-B-aligned 256-B-contiguous store segments.
// Theory: R5's A-persistent gemm counters showed FETCH_SIZE=77MB vs ~8MB of
// input -> write-allocate/RFO reads on the output stream. The rocclr fill
// avoids RFO (1.07GB written, FETCH~0) with dense contiguous dwordx4 waves;
// R8's 128-B segments didn't help -> allocation granule may be 256 B. Here
// each store instruction covers FULL 256-B sectors: lanes 0-15 = one row's
// 64 floats (256 B), 4 rows per instruction.
// Per wave: transpose 32 rows x 64 cols fp32 (8 KB, reusing dead As/Bs LDS)
// x 2 passes. Scatter granule-swizzled (g ^= row&7): write 2-way (free),
// read uniform 8/bank (optimal b128).

#define NROWS 8192
#define DK    256
#define BM    128
#define BN    128
#define BK    64

typedef __bf16 bf16_8 __attribute__((ext_vector_type(8)));
typedef float  f32x4  __attribute__((ext_vector_type(4)));

__device__ __forceinline__ unsigned short f2bf(float f) {
    unsigned int u = __builtin_bit_cast(unsigned int, f);
    u = (u + 0x7FFFu + ((u >> 16) & 1u)) >> 16;  // round-to-nearest-even
    return (unsigned short)u;
}

// ---------------------------------------------------------------------------
// Prep: fp32 -> bf16 conversion + row squared-norms.
// ---------------------------------------------------------------------------
__global__ __launch_bounds__(64) void prep_kernel(
    const float* __restrict__ x, const float* __restrict__ y,
    unsigned short* __restrict__ xb, unsigned short* __restrict__ yb,
    float* __restrict__ x2, float* __restrict__ y2)
{
    const int row  = blockIdx.x;
    const int lane = threadIdx.x;          // 0..63, 4 floats each = 256
    const size_t base = (size_t)row * DK + lane * 4;

    const float4 vx = *(const float4*)(x + base);
    const float4 vy = *(const float4*)(y + base);

    ushort4 hx = make_ushort4(f2bf(vx.x), f2bf(vx.y), f2bf(vx.z), f2bf(vx.w));
    ushort4 hy = make_ushort4(f2bf(vy.x), f2bf(vy.y), f2bf(vy.z), f2bf(vy.w));
    *(ushort4*)(xb + base) = hx;
    *(ushort4*)(yb + base) = hy;

    float sx = vx.x * vx.x + vx.y * vx.y + vx.z * vx.z + vx.w * vx.w;
    float sy = vy.x * vy.x + vy.y * vy.y + vy.z * vy.z + vy.w * vy.w;
    #pragma unroll
    for (int off = 32; off > 0; off >>= 1) {
        sx += __shfl_down(sx, off);
        sy += __shfl_down(sy, off);
    }
    if (lane == 0) {
        x2[row] = sx;
        y2[row] = sy;
    }
}

// ---------------------------------------------------------------------------
// GEMM + fused epilogue. C = x_bf @ y_bf^T with 16x16x32 bf16 MFMA.
// Block = 256 threads = 4 waves in 2x2, each wave owns a 64x64 sub-tile.
// K-loop identical to R1. Epilogue: m-split LDS transpose (see header).
// ---------------------------------------------------------------------------
__global__ __launch_bounds__(256) void gemm_ep_kernel(
    const unsigned short* __restrict__ xb, const unsigned short* __restrict__ yb,
    const float* __restrict__ x2, const float* __restrict__ y2,
    float* __restrict__ out)
{
    // 32 KB: As (16 KB) + Bs (16 KB) during K-loop; reused as 4 x 8 KB
    // per-wave fp32 transpose buffers (32 rows x 64 cols) in the epilogue.
    __shared__ __align__(16) unsigned char smem[2 * BM * BK + 2 * BN * BK];
    unsigned short* As = (unsigned short*)smem;
    unsigned short* Bs = As + BM * BK;

    const int tid  = threadIdx.x;
    const int wave = tid >> 6;
    const int lane = tid & 63;
    const int bm   = blockIdx.x;
    const int bn   = blockIdx.y;

    const int wm = (wave & 1) * 64;   // wave's row offset in 128-tile
    const int wn = (wave >> 1) * 64;  // wave's col offset in 128-tile

    // --- staging: tile is 128 rows x 64 cols bf16 = 16 KB = 16 chunks of
    // 1 KiB. Wave w stages chunks 4w..4w+3 of A and B (8 global_load_lds).
    const int subrow = lane >> 3;                 // 0..7 row within chunk
    const int sslot  = (lane & 7) ^ subrow;       // pre-swizzled global slot
    const size_t laneoff = (size_t)subrow * DK + sslot * 8;

    const unsigned short* gA[4];
    const unsigned short* gB[4];
    unsigned short* lA[4];
    unsigned short* lB[4];
    #pragma unroll
    for (int m = 0; m < 4; ++m) {
        const int c = wave * 4 + m;               // chunk id, rows c*8..c*8+7
        gA[m] = xb + (size_t)(bm * BM + c * 8) * DK + laneoff;
        gB[m] = yb + (size_t)(bn * BN + c * 8) * DK + laneoff;
        lA[m] = &As[c * 512];                     // 512 ushort = 1 KiB
        lB[m] = &Bs[c * 512];
    }

    f32x4 acc[4][4];
    #pragma unroll
    for (int i = 0; i < 4; ++i)
        #pragma unroll
        for (int j = 0; j < 4; ++j)
            acc[i][j] = (f32x4){0.f, 0.f, 0.f, 0.f};

    const int quad = lane >> 4;   // 0..3
    const int l15  = lane & 15;
    const int l7   = l15 & 7;     // == row&7 for every fragment row we read

    const int rbaseA = (wm + l15) * BK;   // ushort index of row start
    const int rbaseB = (wn + l15) * BK;

    #pragma unroll
    for (int kt = 0; kt < DK; kt += BK) {
        #pragma unroll
        for (int m = 0; m < 4; ++m) {
            __builtin_amdgcn_global_load_lds(
                (const __attribute__((address_space(1))) void*)(gA[m] + kt),
                (__attribute__((address_space(3))) void*)lA[m], 16, 0, 0);
            __builtin_amdgcn_global_load_lds(
                (const __attribute__((address_space(1))) void*)(gB[m] + kt),
                (__attribute__((address_space(3))) void*)lB[m], 16, 0, 0);
        }
        __syncthreads();

        // Two K-steps of 32 from this 64-wide tile.
        #pragma unroll
        for (int kk = 0; kk < 2; ++kk) {
            const int slot = ((kk << 2) | quad) ^ l7;   // swizzled 16-B slot
            bf16_8 afr[4], bfr[4];
            #pragma unroll
            for (int i = 0; i < 4; ++i)
                afr[i] = *(const bf16_8*)&As[rbaseA + i * 16 * BK + slot * 8];
            #pragma unroll
            for (int j = 0; j < 4; ++j)
                bfr[j] = *(const bf16_8*)&Bs[rbaseB + j * 16 * BK + slot * 8];

            #pragma unroll
            for (int i = 0; i < 4; ++i)
                #pragma unroll
                for (int j = 0; j < 4; ++j)
                    acc[i][j] = __builtin_amdgcn_mfma_f32_16x16x32_bf16(
                        afr[i], bfr[j], acc[i][j], 0, 0, 0);
        }
        __syncthreads();   // last iter: all waves done with As/Bs -> reusable
    }

    // --- m-split transposed epilogue ---------------------------------------
    // C/D layout (m89/m91): wave-local row = i*16 + quad*4 + r,
    //                       wave-local col = l15 + j*16.
    // Pass ip handles rows ip*32..ip*32+31 (i = ip*2, ip*2+1) in a
    // [32 rows][64 cols] fp32 LDS buffer, row stride 256 B.
    // Granule swizzle: 16-B granule g of row lr lives at g ^ (lr&7).
    float* Ep = (float*)smem + wave * 2048;   // this wave's 8 KB

    const int mT = bm * BM + wm;
    const int nT = bn * BN + wn;

    float y2v[4];
    #pragma unroll
    for (int j = 0; j < 4; ++j) y2v[j] = y2[nT + l15 + j * 16];

    const int rg = lane >> 4;     // 0..3  read-back row within group
    const int cl = lane & 15;     // 0..15 read-back granule (=16B of a row)

    #pragma unroll
    for (int ip = 0; ip < 2; ++ip) {
        // scatter (transpose staging), rows ip*32 .. ip*32+31
        #pragma unroll
        for (int i2 = 0; i2 < 2; ++i2) {
            const int i = ip * 2 + i2;
            #pragma unroll
            for (int r = 0; r < 4; ++r) {
                const int lr  = i2 * 16 + quad * 4 + r;      // 0..31
                const float xv = x2[mT + ip * 32 + lr];
                const int key = lr & 7;
                float* erow = Ep + lr * 64;
                #pragma unroll
                for (int j = 0; j < 4; ++j) {
                    const int col = l15 + j * 16;            // 0..63
                    const float xy = acc[i][j][r];
                    float s = xv + y2v[j] - 2.0f * xy;
                    s = fmaxf(s, 0.0f);
                    const float e  = __expf(-0.5f * s);
                    const float pq = xy + 1.0f;
                    erow[(((col >> 2) ^ key) << 2) + (col & 3)] =
                        fmaf(0.1f, pq * pq * pq, e);
                }
            }
        }
        // read back transposed; store 256-B contiguous per 16 lanes.
        // (wave-internal LDS dependency; compiler inserts lgkmcnt waits)
        #pragma unroll
        for (int p = 0; p < 8; ++p) {
            const int lr = p * 4 + rg;                       // 0..31
            const int gs = cl ^ (lr & 7);                    // swizzled granule
            const f32x4 v4 = *(const f32x4*)&Ep[lr * 64 + gs * 4];
            *(f32x4*)&out[(size_t)(mT + ip * 32 + lr) * NROWS + nT + cl * 4] = v4;
        }
    }
}

// ---------------------------------------------------------------------------
extern "C" void kernel_launch(void* const* d_in, const int* in_sizes, int n_in,
                              void* d_out, int out_size, void* d_ws, size_t ws_size,
                              hipStream_t stream) {
    const float* x = (const float*)d_in[0];
    const float* y = (const float*)d_in[1];
    float* out = (float*)d_out;

    char* ws = (char*)d_ws;
    unsigned short* xb = (unsigned short*)ws;                                  // 4 MB
    unsigned short* yb = (unsigned short*)(ws + (size_t)NROWS * DK * 2);       // 4 MB
    float* x2 = (float*)(ws + (size_t)2 * NROWS * DK * 2);                     // 32 KB
    float* y2 = x2 + NROWS;                                                    // 32 KB

    prep_kernel<<<NROWS, 64, 0, stream>>>(x, y, xb, yb, x2, y2);

    dim3 grid(NROWS / BM, NROWS / BN);
    gemm_ep_kernel<<<grid, 256, 0, stream>>>(xb, yb, x2, y2, out);
}